// Round 4
// baseline (54533.490 us; speedup 1.0000x reference)
//
#include <hip/hip_runtime.h>
#include <math.h>

#define BB 64      // batch
#define KK 4       // beam width
#define RR 256     // KK*BB rows
#define DD 512
#define HH 512
#define T3 1536
#define VV 50257
#define NSTR 393   // ceil(VV/128)

struct SRec {       // per (row, stripe) record, 48 B
  float v[4];       // stripe top-4 logits (desc, idx-asc on ties)
  int   ix[4];
  float ms;         // stripe max (== v[0])
  float pad;
  double S;         // sum expf(v - ms) over stripe, fp64 accumulated
};

__global__ __launch_bounds__(256) void k_init(const int* __restrict__ xs,
                                              float* __restrict__ hCur,
                                              float* __restrict__ scores,
                                              int* __restrict__ curx) {
  int i = blockIdx.x * 256 + threadIdx.x;
  if (i < HH * RR) hCur[i] = 0.0f;
  if (i < RR) {
    scores[i] = 0.0f;
    curx[i] = xs[i & 63];
  }
}

// GRU for 256 beam-rows, fp32, fixed sequential k-order (deterministic, so
// bit-identical beam rows stay bit-identical). grid (64 jg, 4 rowgroup).
__global__ __launch_bounds__(256) void k_gru(const float* __restrict__ Etab,
                                             const float* __restrict__ Wih,
                                             const float* __restrict__ Whh,
                                             const float* __restrict__ bih,
                                             const float* __restrict__ bhh,
                                             const float* __restrict__ hCur,
                                             float* __restrict__ hStage,
                                             const int* __restrict__ curx) {
  const int tid = threadIdx.x;
  const int jloc = tid & 7;
  const int bg = tid >> 3;
  const int j = blockIdx.x * 8 + jloc;
  const int rowbase = blockIdx.y * 64;
  const int b0 = bg * 2;  // local row pair within group

  __shared__ float xe[64 * 33];
  __shared__ float hp[64 * 33];
  __shared__ int xl[64];
  if (tid < 64) xl[tid] = curx[rowbase + tid];

  float a[12];
#pragma unroll
  for (int i = 0; i < 12; ++i) a[i] = 0.0f;

  for (int kt = 0; kt < 16; ++kt) {
    __syncthreads();
    const int kb = kt * 32;
#pragma unroll
    for (int i = 0; i < 8; ++i) {
      int idx = i * 256 + tid;
      int b = idx >> 5, kk = idx & 31;
      xe[b * 33 + kk] = Etab[(size_t)xl[b] * DD + kb + kk];
    }
#pragma unroll
    for (int i = 0; i < 8; ++i) {
      int idx = i * 256 + tid;
      int kk = idx >> 6, bl = idx & 63;
      hp[bl * 33 + kk] = hCur[(size_t)(kb + kk) * RR + rowbase + bl];
    }
    __syncthreads();
#pragma unroll 4
    for (int kk = 0; kk < 32; ++kk) {
      const size_t krow = (size_t)(kb + kk) * T3;
      float wir = Wih[krow + j];
      float wiz = Wih[krow + j + HH];
      float wig = Wih[krow + j + 2 * HH];
      float whr = Whh[krow + j];
      float whz = Whh[krow + j + HH];
      float whg = Whh[krow + j + 2 * HH];
      float x0v = xe[b0 * 33 + kk];
      float x1v = xe[(b0 + 1) * 33 + kk];
      float h0v = hp[b0 * 33 + kk];
      float h1v = hp[(b0 + 1) * 33 + kk];
      a[0] += x0v * wir; a[1]  += x0v * wiz; a[2]  += x0v * wig;
      a[3] += h0v * whr; a[4]  += h0v * whz; a[5]  += h0v * whg;
      a[6] += x1v * wir; a[7]  += x1v * wiz; a[8]  += x1v * wig;
      a[9] += h1v * whr; a[10] += h1v * whz; a[11] += h1v * whg;
    }
  }

  const float bir = bih[j], biz = bih[HH + j], big = bih[2 * HH + j];
  const float bhr = bhh[j], bhz = bhh[HH + j], bhg = bhh[2 * HH + j];
#pragma unroll
  for (int p = 0; p < 2; ++p) {
    const int row = rowbase + b0 + p;
    float ir = a[6 * p + 0] + bir;
    float iz = a[6 * p + 1] + biz;
    float ig = a[6 * p + 2] + big;
    float hr = a[6 * p + 3] + bhr;
    float hz = a[6 * p + 4] + bhz;
    float hg = a[6 * p + 5] + bhg;
    float r = 1.0f / (1.0f + expf(-(ir + hr)));
    float z = 1.0f / (1.0f + expf(-(iz + hz)));
    float n = tanhf(ig + r * hg);
    float hprev = hCur[(size_t)j * RR + row];
    hStage[(size_t)j * RR + row] = (1.0f - z) * n + z * hprev;
  }
}

// Merge two sorted-4 lists (desc value, asc index on ties), keep top-4.
__device__ inline void merge44(float* v, int* ix, const float* ov, const int* oix) {
  float rv[4]; int rix[4];
  int a = 0, b = 0;
#pragma unroll
  for (int t = 0; t < 4; ++t) {
    bool ta;
    if (a >= 4) ta = false;
    else if (b >= 4) ta = true;
    else ta = (v[a] > ov[b]) || (v[a] == ov[b] && ix[a] < oix[b]);
    if (ta) { rv[t] = v[a]; rix[t] = ix[a]; ++a; }
    else    { rv[t] = ov[b]; rix[t] = oix[b]; ++b; }
  }
#pragma unroll
  for (int t = 0; t < 4; ++t) { v[t] = rv[t]; ix[t] = rix[t]; }
}

// logits (fp32) for 256 rows; per (row, 128-col stripe): top-4 by value
// (idx-asc ties) + stripe max + stripe exp-sum. grid (393, 2 rowgroups of
// 128 rows), block 256 = 4 waves x 32 rows.
// v5: as v4 (no LDS, no barriers, ping-pong W in VGPRs, wave-uniform
// scalar h) but 32 rows per wave: 64 FMA per kk per 2 W loads (2x the
// arithmetic intensity), halving both the per-FMA overhead and the
// wave count (3144 waves) while W-fetch demand halves (grid.y 4->2).
// ALL array indexing is compile-time static (round-2 scratch lesson).
// FMA accumulation order (k ascending, single fmac chain per row/col) is
// bit-identical to all previous versions; stripes/SRec unchanged.
__global__ __launch_bounds__(256) void k_logits(const float* __restrict__ Wout,
                                                const float* __restrict__ bout,
                                                const float* __restrict__ hStage,
                                                SRec* __restrict__ sbuf) {
  const int s = blockIdx.x;
  const int tid = threadIdx.x;
  const int wid = tid >> 6;     // wave -> local rows wid*32 .. +31
  const int ct = tid & 63;
  const int scol = s * 128;
  const int c0 = scol + ct;
  const bool okA = (c0 < VV);
  const bool okB = (c0 + 64 < VV);
  const int cA = okA ? c0 : (VV - 1);
  const int cB = okB ? (c0 + 64) : (VV - 1);
  // wave-uniform row base (forced uniform -> scalar loads for h)
  const int rowU = __builtin_amdgcn_readfirstlane(blockIdx.y * 128 + wid * 32);

  const float* __restrict__ WA = Wout + cA;   // per-lane column base, stride VV
  const float* __restrict__ WB = Wout + cB;

  float acc[32][2];
#pragma unroll
  for (int ri = 0; ri < 32; ++ri) { acc[ri][0] = 0.0f; acc[ri][1] = 0.0f; }

  float wA0[4], wB0[4], wA1[4], wB1[4];

  auto loadW = [&](float* wA, float* wB, int kb) {
#pragma unroll
    for (int i = 0; i < 4; ++i) {
      wA[i] = WA[(size_t)(kb + i) * VV];
      wB[i] = WB[(size_t)(kb + i) * VV];
    }
  };
  auto fmaC = [&](const float* wA, const float* wB, int kb) {
#pragma unroll
    for (int i = 0; i < 4; ++i) {
      // 32 h values for this wave's rows: 128 B of uniform (scalar) fetch
      const float4* hg = reinterpret_cast<const float4*>(
          hStage + (size_t)(kb + i) * RR + rowU);
      float4 h0 = hg[0], h1 = hg[1], h2 = hg[2], h3 = hg[3];
      float4 h4 = hg[4], h5 = hg[5], h6 = hg[6], h7 = hg[7];
      float hr[32] = {h0.x, h0.y, h0.z, h0.w, h1.x, h1.y, h1.z, h1.w,
                      h2.x, h2.y, h2.z, h2.w, h3.x, h3.y, h3.z, h3.w,
                      h4.x, h4.y, h4.z, h4.w, h5.x, h5.y, h5.z, h5.w,
                      h6.x, h6.y, h6.z, h6.w, h7.x, h7.y, h7.z, h7.w};
#pragma unroll
      for (int ri = 0; ri < 32; ++ri) {
        acc[ri][0] += hr[ri] * wA[i];
        acc[ri][1] += hr[ri] * wB[i];
      }
    }
  };

  loadW(wA0, wB0, 0);
  for (int c = 0; c < 128; c += 2) {        // 128 groups of 4 k
    loadW(wA1, wB1, (c + 1) * 4);           // prefetch odd group
    fmaC(wA0, wB0, c * 4);                  // consume even group
    if (c + 2 < 128) loadW(wA0, wB0, (c + 2) * 4);  // prefetch next even
    fmaC(wA1, wB1, (c + 1) * 4);            // consume odd group
  }

  const float boA = bout[cA];
  const float boB = bout[cB];
#pragma unroll
  for (int ri = 0; ri < 32; ++ri) {         // FULL unroll: static acc indices
    float vA = okA ? (acc[ri][0] + boA) : -INFINITY;
    float vB = okB ? (acc[ri][1] + boB) : -INFINITY;
    // per-lane sorted-2 (pad to 4); cA < cB so tie keeps cA first
    float v[4]; int ix[4];
    if (vB > vA) { v[0] = vB; ix[0] = c0 + 64; v[1] = vA; ix[1] = okA ? c0 : 0x7fffffff; }
    else         { v[0] = vA; ix[0] = okA ? c0 : 0x7fffffff; v[1] = vB; ix[1] = okB ? (c0 + 64) : 0x7fffffff; }
    v[2] = -INFINITY; ix[2] = 0x7fffffff;
    v[3] = -INFINITY; ix[3] = 0x7fffffff;
    // butterfly merge across 64 lanes -> wave-wide top-4 (all lanes agree)
#pragma unroll
    for (int m = 1; m < 64; m <<= 1) {
      float ov[4]; int oix[4];
#pragma unroll
      for (int jj = 0; jj < 4; ++jj) {
        ov[jj] = __shfl_xor(v[jj], m, 64);
        oix[jj] = __shfl_xor(ix[jj], m, 64);
      }
      merge44(v, ix, ov, oix);
    }
    const float ms = v[0];
    double sl = 0.0;
    if (okA) sl += (double)expf(vA - ms);
    if (okB) sl += (double)expf(vB - ms);
#pragma unroll
    for (int m = 1; m < 64; m <<= 1) sl += __shfl_xor(sl, m, 64);
    if (ct == 0) {
      const int row = rowU + ri;
      SRec* rec = &sbuf[(size_t)row * NSTR + s];
#pragma unroll
      for (int jj = 0; jj < 4; ++jj) { rec->v[jj] = v[jj]; rec->ix[jj] = ix[jj]; }
      rec->ms = ms;
      rec->S = sl;
    }
  }
}

// Merge a sorted-4 list into a sorted-8 list (keep top-8).
__device__ inline void merge84(float* v, int* ix, const float* ov, const int* oix) {
  float rv[8]; int rix[8];
  int a = 0, b = 0;
#pragma unroll
  for (int t = 0; t < 8; ++t) {
    bool ta;
    if (a >= 8) ta = false;
    else if (b >= 4) ta = true;
    else ta = (v[a] > ov[b]) || (v[a] == ov[b] && ix[a] < oix[b]);
    if (ta) { rv[t] = v[a]; rix[t] = ix[a]; ++a; }
    else    { rv[t] = ov[b]; rix[t] = oix[b]; ++b; }
  }
#pragma unroll
  for (int t = 0; t < 8; ++t) { v[t] = rv[t]; ix[t] = rix[t]; }
}

__device__ inline void merge88(float* v, int* ix, const float* ov, const int* oix) {
  float rv[8]; int rix[8];
  int a = 0, b = 0;
#pragma unroll
  for (int t = 0; t < 8; ++t) {
    bool ta;
    if (a >= 8) ta = false;
    else if (b >= 8) ta = true;
    else ta = (v[a] > ov[b]) || (v[a] == ov[b] && ix[a] < oix[b]);
    if (ta) { rv[t] = v[a]; rix[t] = ix[a]; ++a; }
    else    { rv[t] = ov[b]; rix[t] = oix[b]; ++b; }
  }
#pragma unroll
  for (int t = 0; t < 8; ++t) { v[t] = rv[t]; ix[t] = rix[t]; }
}

// Per row: global top-8 by raw value, fp64 Z, then emulate fp32 log_softmax
// q = fl32(fl32(v-m) - L32) and output top-4 by (q desc, idx asc).
__global__ __launch_bounds__(64) void k_merge(const SRec* __restrict__ sbuf,
                                              float* __restrict__ topq,
                                              int* __restrict__ topi) {
  const int row = blockIdx.x;
  const int l = threadIdx.x;
  float lv[8]; int li[8];
#pragma unroll
  for (int jj = 0; jj < 8; ++jj) { lv[jj] = -INFINITY; li[jj] = 0x7fffffff; }
  float lms[7]; double lS[7];
  int ns = 0;
  for (int s = l; s < NSTR; s += 64) {
    const SRec* rec = &sbuf[(size_t)row * NSTR + s];
    float mv[4]; int mi[4];
#pragma unroll
    for (int jj = 0; jj < 4; ++jj) { mv[jj] = rec->v[jj]; mi[jj] = rec->ix[jj]; }
    lms[ns] = rec->ms;
    lS[ns] = rec->S;
    ++ns;
    merge84(lv, li, mv, mi);
  }
#pragma unroll
  for (int m = 1; m < 64; m <<= 1) {
    float ov[8]; int oi[8];
#pragma unroll
    for (int jj = 0; jj < 8; ++jj) {
      ov[jj] = __shfl_xor(lv[jj], m, 64);
      oi[jj] = __shfl_xor(li[jj], m, 64);
    }
    merge88(lv, li, ov, oi);
  }
  const float mg = lv[0];  // global max logit
  double Z = 0.0;
  for (int i = 0; i < ns; ++i) Z += lS[i] * (double)expf(lms[i] - mg);
#pragma unroll
  for (int m = 1; m < 64; m <<= 1) Z += __shfl_xor(Z, m, 64);
  const float Zf = (float)Z;
  const float L32 = (float)log((double)Zf);
  // fp32-quantized logp for top-8, re-sort by (q desc, idx asc)
  float q[8];
#pragma unroll
  for (int jj = 0; jj < 8; ++jj) {
    float g = lv[jj] - mg;   // fp32 sub
    q[jj] = g - L32;         // fp32 sub -> the ref's logp quantization
  }
  // insertion sort of 8 (full order comparator: q desc, idx asc)
  float sq[8]; int si[8];
#pragma unroll
  for (int jj = 0; jj < 8; ++jj) {
    float cv = q[jj]; int ci = li[jj];
    int pos = jj;
    for (int kk2 = 0; kk2 < jj; ++kk2) {
      if (cv > sq[kk2] || (cv == sq[kk2] && ci < si[kk2])) { pos = kk2; break; }
    }
    for (int kk2 = jj; kk2 > pos; --kk2) { sq[kk2] = sq[kk2 - 1]; si[kk2] = si[kk2 - 1]; }
    sq[pos] = cv; si[pos] = ci;
  }
  if (l == 0) {
#pragma unroll
    for (int jj = 0; jj < 4; ++jj) {
      topq[row * 4 + jj] = sq[jj];
      topi[row * 4 + jj] = si[jj];
    }
  }
}

// Beam transition per batch row: trans[f*4+to] = fl32(score_f + q), stable
// top-4 of 16 (flat-index ascending on ties == jnp stable argsort).
__global__ __launch_bounds__(64) void k_beam(const float* __restrict__ topq,
                                             const int* __restrict__ topi,
                                             float* __restrict__ scores,
                                             int* __restrict__ curx,
                                             int* __restrict__ bfrom) {
  const int b = threadIdx.x;  // 0..63
  float sc[4];
#pragma unroll
  for (int f = 0; f < 4; ++f) sc[f] = scores[f * 64 + b];
  float tv[16];
#pragma unroll
  for (int f = 0; f < 4; ++f)
#pragma unroll
    for (int to = 0; to < 4; ++to)
      tv[f * 4 + to] = sc[f] + topq[(f * 64 + b) * 4 + to];  // fp32 add

  float ov[4]; int ord[4]; int cnt = 0;
#pragma unroll
  for (int flat = 0; flat < 16; ++flat) {
    float v = tv[flat];
    int pos = -1;
    for (int j = 0; j < cnt; ++j)
      if (v > ov[j]) { pos = j; break; }   // strict: stable on equals
    if (pos < 0) {
      if (cnt < 4) { ov[cnt] = v; ord[cnt] = flat; ++cnt; }
    } else {
      int last = (cnt < 4) ? cnt : 3;
      for (int j = last; j > pos; --j) { ov[j] = ov[j - 1]; ord[j] = ord[j - 1]; }
      ov[pos] = v; ord[pos] = flat;
      if (cnt < 4) ++cnt;
    }
  }
#pragma unroll
  for (int s = 0; s < 4; ++s) {
    int flat = ord[s];
    int f = flat >> 2, to = flat & 3;
    int tok = topi[(f * 64 + b) * 4 + to];
    scores[s * 64 + b] = ov[s];
    curx[s * 64 + b] = tok;
    bfrom[s * 64 + b] = f;
  }
}

// Gather hidden states by source beam: hCur[j, s*64+b] = hStage[j, bfrom*64+b].
__global__ __launch_bounds__(256) void k_hgather(const float* __restrict__ hStage,
                                                 float* __restrict__ hCur,
                                                 const int* __restrict__ bfrom) {
  int idx = blockIdx.x * 256 + threadIdx.x;  // HH*RR = 131072
  int j = idx >> 8, r = idx & 255;
  int s = r >> 6, b = r & 63;
  hCur[(size_t)j * RR + r] = hStage[(size_t)j * RR + bfrom[s * 64 + b] * 64 + b];
}

// Gather sequences + append new token at position t. seqs layout [b][k][T].
__global__ __launch_bounds__(256) void k_seq(const int* __restrict__ src,
                                             int* __restrict__ dst,
                                             const int* __restrict__ bfrom,
                                             const int* __restrict__ curx,
                                             int t, int T) {
  int tid = threadIdx.x;  // 256 = 4 slots x 64 rows
  int s = tid >> 6, b = tid & 63;
  int bf = bfrom[s * 64 + b];
  for (int u = 0; u < t; ++u)
    dst[(b * KK + s) * T + u] = src[(b * KK + bf) * T + u];
  dst[(b * KK + s) * T + t] = curx[s * 64 + b];
}

__global__ __launch_bounds__(256) void k_out(const int* __restrict__ seqs,
                                             int* __restrict__ outp, int T) {
  int idx = blockIdx.x * 256 + threadIdx.x;
  if (idx < BB * T) {
    int b = idx / T, u = idx % T;
    outp[b * T + u] = seqs[(b * KK + 0) * T + u];
  }
}

extern "C" void kernel_launch(void* const* d_in, const int* in_sizes, int n_in,
                              void* d_out, int out_size, void* d_ws, size_t ws_size,
                              hipStream_t stream) {
  (void)in_sizes; (void)n_in; (void)ws_size;
  const int* xs = (const int*)d_in[0];
  const float* Etab = (const float*)d_in[1];
  const float* Wih = (const float*)d_in[2];
  const float* Whh = (const float*)d_in[3];
  const float* bih = (const float*)d_in[4];
  const float* bhh = (const float*)d_in[5];
  const float* Wout = (const float*)d_in[6];
  const float* bout = (const float*)d_in[7];
  int* outp = (int*)d_out;
  const int T = out_size / BB;  // 16

  // workspace carve (~6 MB)
  SRec* sbuf = (SRec*)d_ws;                       // 256*393*48 B
  float* hCur = (float*)(sbuf + (size_t)RR * NSTR);
  float* hStage = hCur + (size_t)HH * RR;
  float* topq = hStage + (size_t)HH * RR;         // RR*4 f
  int* topi = (int*)(topq + RR * 4);              // RR*4 i
  float* scores = (float*)(topi + RR * 4);        // RR f
  int* curx = (int*)(scores + RR);                // RR i
  int* bfrom = curx + RR;                         // RR i
  int* seqA = bfrom + RR;                         // BB*KK*T i
  int* seqB = seqA + BB * KK * T;                 // BB*KK*T i

  k_init<<<dim3(512), dim3(256), 0, stream>>>(xs, hCur, scores, curx);
  for (int t = 0; t < T; ++t) {
    int* ssrc = (t % 2 == 0) ? seqA : seqB;
    int* sdst = (t % 2 == 0) ? seqB : seqA;
    k_gru<<<dim3(64, 4), dim3(256), 0, stream>>>(Etab, Wih, Whh, bih, bhh,
                                                 hCur, hStage, curx);
    k_logits<<<dim3(NSTR, 2), dim3(256), 0, stream>>>(Wout, bout, hStage, sbuf);
    k_merge<<<dim3(RR), dim3(64), 0, stream>>>(sbuf, topq, topi);
    k_beam<<<dim3(1), dim3(64), 0, stream>>>(topq, topi, scores, curx, bfrom);
    k_hgather<<<dim3(512), dim3(256), 0, stream>>>(hStage, hCur, bfrom);
    k_seq<<<dim3(1), dim3(256), 0, stream>>>(ssrc, sdst, bfrom, curx, t, T);
  }
  int* sfin = (T % 2 == 0) ? seqA : seqB;
  k_out<<<dim3((BB * T + 255) / 256), dim3(256), 0, stream>>>(sfin, outp, T);
}

// Round 5
// 24803.606 us; speedup vs baseline: 2.1986x; 2.1986x over previous
//
#include <hip/hip_runtime.h>
#include <math.h>

#define BB 64      // batch
#define KK 4       // beam width
#define RR 256     // KK*BB rows
#define DD 512
#define HH 512
#define T3 1536
#define VV 50257
#define NSTR 393   // ceil(VV/128)

struct SRec {       // per (row, stripe) record, 48 B
  float v[4];       // stripe top-4 logits (desc, idx-asc on ties)
  int   ix[4];
  float ms;         // stripe max (== v[0])
  float pad;
  double S;         // sum expf(v - ms) over stripe, fp64 accumulated
};

__global__ __launch_bounds__(256) void k_init(const int* __restrict__ xs,
                                              float* __restrict__ hCur,
                                              float* __restrict__ scores,
                                              int* __restrict__ curx) {
  int i = blockIdx.x * 256 + threadIdx.x;
  if (i < HH * RR) hCur[i] = 0.0f;
  if (i < RR) {
    scores[i] = 0.0f;
    curx[i] = xs[i & 63];
  }
}

// GRU for 256 beam-rows, fp32, fixed sequential k-order (deterministic, so
// bit-identical beam rows stay bit-identical). grid (64 jg, 4 rowgroup).
__global__ __launch_bounds__(256) void k_gru(const float* __restrict__ Etab,
                                             const float* __restrict__ Wih,
                                             const float* __restrict__ Whh,
                                             const float* __restrict__ bih,
                                             const float* __restrict__ bhh,
                                             const float* __restrict__ hCur,
                                             float* __restrict__ hStage,
                                             const int* __restrict__ curx) {
  const int tid = threadIdx.x;
  const int jloc = tid & 7;
  const int bg = tid >> 3;
  const int j = blockIdx.x * 8 + jloc;
  const int rowbase = blockIdx.y * 64;
  const int b0 = bg * 2;  // local row pair within group

  __shared__ float xe[64 * 33];
  __shared__ float hp[64 * 33];
  __shared__ int xl[64];
  if (tid < 64) xl[tid] = curx[rowbase + tid];

  float a[12];
#pragma unroll
  for (int i = 0; i < 12; ++i) a[i] = 0.0f;

  for (int kt = 0; kt < 16; ++kt) {
    __syncthreads();
    const int kb = kt * 32;
#pragma unroll
    for (int i = 0; i < 8; ++i) {
      int idx = i * 256 + tid;
      int b = idx >> 5, kk = idx & 31;
      xe[b * 33 + kk] = Etab[(size_t)xl[b] * DD + kb + kk];
    }
#pragma unroll
    for (int i = 0; i < 8; ++i) {
      int idx = i * 256 + tid;
      int kk = idx >> 6, bl = idx & 63;
      hp[bl * 33 + kk] = hCur[(size_t)(kb + kk) * RR + rowbase + bl];
    }
    __syncthreads();
#pragma unroll 4
    for (int kk = 0; kk < 32; ++kk) {
      const size_t krow = (size_t)(kb + kk) * T3;
      float wir = Wih[krow + j];
      float wiz = Wih[krow + j + HH];
      float wig = Wih[krow + j + 2 * HH];
      float whr = Whh[krow + j];
      float whz = Whh[krow + j + HH];
      float whg = Whh[krow + j + 2 * HH];
      float x0v = xe[b0 * 33 + kk];
      float x1v = xe[(b0 + 1) * 33 + kk];
      float h0v = hp[b0 * 33 + kk];
      float h1v = hp[(b0 + 1) * 33 + kk];
      a[0] += x0v * wir; a[1]  += x0v * wiz; a[2]  += x0v * wig;
      a[3] += h0v * whr; a[4]  += h0v * whz; a[5]  += h0v * whg;
      a[6] += x1v * wir; a[7]  += x1v * wiz; a[8]  += x1v * wig;
      a[9] += h1v * whr; a[10] += h1v * whz; a[11] += h1v * whg;
    }
  }

  const float bir = bih[j], biz = bih[HH + j], big = bih[2 * HH + j];
  const float bhr = bhh[j], bhz = bhh[HH + j], bhg = bhh[2 * HH + j];
#pragma unroll
  for (int p = 0; p < 2; ++p) {
    const int row = rowbase + b0 + p;
    float ir = a[6 * p + 0] + bir;
    float iz = a[6 * p + 1] + biz;
    float ig = a[6 * p + 2] + big;
    float hr = a[6 * p + 3] + bhr;
    float hz = a[6 * p + 4] + bhz;
    float hg = a[6 * p + 5] + bhg;
    float r = 1.0f / (1.0f + expf(-(ir + hr)));
    float z = 1.0f / (1.0f + expf(-(iz + hz)));
    float n = tanhf(ig + r * hg);
    float hprev = hCur[(size_t)j * RR + row];
    hStage[(size_t)j * RR + row] = (1.0f - z) * n + z * hprev;
  }
}

// Merge two sorted-4 lists (desc value, asc index on ties), keep top-4.
__device__ inline void merge44(float* v, int* ix, const float* ov, const int* oix) {
  float rv[4]; int rix[4];
  int a = 0, b = 0;
#pragma unroll
  for (int t = 0; t < 4; ++t) {
    bool ta;
    if (a >= 4) ta = false;
    else if (b >= 4) ta = true;
    else ta = (v[a] > ov[b]) || (v[a] == ov[b] && ix[a] < oix[b]);
    if (ta) { rv[t] = v[a]; rix[t] = ix[a]; ++a; }
    else    { rv[t] = ov[b]; rix[t] = oix[b]; ++b; }
  }
#pragma unroll
  for (int t = 0; t < 4; ++t) { v[t] = rv[t]; ix[t] = rix[t]; }
}

// logits (fp32) for 256 rows; per (row, 128-col stripe): top-4 by value
// (idx-asc ties) + stripe max + stripe exp-sum. grid (393, 2 rowgroups of
// 128 rows), block 256 = 4 waves x 32 rows.
// v6: v5's geometry (32 rows/wave, no LDS, no barriers, ping-pong W,
// wave-uniform scalar h) but SPILL-PROOF codegen: no lambdas, no
// address-taken local arrays, no float* passing. W ping/pong = 16 named
// scalars; h consumed straight from float4 components; acc[32][2] touched
// only with literal-constant indices (macros + full unroll). Round-4
// lesson: pointer-escaped locals lose SROA -> 6.75 GB scratch traffic.
// FMA accumulation order (k ascending, single fmac chain per row/col) is
// bit-identical to all previous versions; stripes/SRec unchanged.
__global__ __launch_bounds__(256) void k_logits(const float* __restrict__ Wout,
                                                const float* __restrict__ bout,
                                                const float* __restrict__ hStage,
                                                SRec* __restrict__ sbuf) {
  const int s = blockIdx.x;
  const int tid = threadIdx.x;
  const int wid = tid >> 6;     // wave -> local rows wid*32 .. +31
  const int ct = tid & 63;
  const int scol = s * 128;
  const int c0 = scol + ct;
  const bool okA = (c0 < VV);
  const bool okB = (c0 + 64 < VV);
  const int cA = okA ? c0 : (VV - 1);
  const int cB = okB ? (c0 + 64) : (VV - 1);
  // wave-uniform row base (forced uniform -> scalar loads for h)
  const int rowU = __builtin_amdgcn_readfirstlane(blockIdx.y * 128 + wid * 32);

  const float* __restrict__ WA = Wout + cA;   // per-lane column base, stride VV
  const float* __restrict__ WB = Wout + cB;

  float acc[32][2];
#pragma unroll
  for (int ri = 0; ri < 32; ++ri) { acc[ri][0] = 0.0f; acc[ri][1] = 0.0f; }

  // W ping (p*) / pong (q*) buffers: named scalars, never address-taken.
  float pA0, pA1, pA2, pA3, pB0, pB1, pB2, pB3;
  float qA0, qA1, qA2, qA3, qB0, qB1, qB2, qB3;

#define LOADW_P(kb) {                                              \
    pA0 = WA[(size_t)((kb) + 0) * VV]; pB0 = WB[(size_t)((kb) + 0) * VV]; \
    pA1 = WA[(size_t)((kb) + 1) * VV]; pB1 = WB[(size_t)((kb) + 1) * VV]; \
    pA2 = WA[(size_t)((kb) + 2) * VV]; pB2 = WB[(size_t)((kb) + 2) * VV]; \
    pA3 = WA[(size_t)((kb) + 3) * VV]; pB3 = WB[(size_t)((kb) + 3) * VV]; }
#define LOADW_Q(kb) {                                              \
    qA0 = WA[(size_t)((kb) + 0) * VV]; qB0 = WB[(size_t)((kb) + 0) * VV]; \
    qA1 = WA[(size_t)((kb) + 1) * VV]; qB1 = WB[(size_t)((kb) + 1) * VV]; \
    qA2 = WA[(size_t)((kb) + 2) * VV]; qB2 = WB[(size_t)((kb) + 2) * VV]; \
    qA3 = WA[(size_t)((kb) + 3) * VV]; qB3 = WB[(size_t)((kb) + 3) * VV]; }

  // 4 rows of FMA from one float4 of h; all acc indices literal constants.
#define FMA_QUAD(g, base, wa, wb) {                       \
    acc[(base) + 0][0] += (g).x * (wa); acc[(base) + 0][1] += (g).x * (wb); \
    acc[(base) + 1][0] += (g).y * (wa); acc[(base) + 1][1] += (g).y * (wb); \
    acc[(base) + 2][0] += (g).z * (wa); acc[(base) + 2][1] += (g).z * (wb); \
    acc[(base) + 3][0] += (g).w * (wa); acc[(base) + 3][1] += (g).w * (wb); }

  // One k-step: 128 B wave-uniform h fetch + 64 FMAs.
#define FMA_STEP(wa, wb, kabs) {                                          \
    const float4* hg = reinterpret_cast<const float4*>(                   \
        hStage + (size_t)(kabs) * RR + rowU);                             \
    const float4 g0 = hg[0], g1 = hg[1], g2 = hg[2], g3 = hg[3];          \
    const float4 g4 = hg[4], g5 = hg[5], g6 = hg[6], g7 = hg[7];          \
    FMA_QUAD(g0,  0, wa, wb) FMA_QUAD(g1,  4, wa, wb)                     \
    FMA_QUAD(g2,  8, wa, wb) FMA_QUAD(g3, 12, wa, wb)                     \
    FMA_QUAD(g4, 16, wa, wb) FMA_QUAD(g5, 20, wa, wb)                     \
    FMA_QUAD(g6, 24, wa, wb) FMA_QUAD(g7, 28, wa, wb) }

#define FMA_GRP_P(kb) { FMA_STEP(pA0, pB0, (kb) + 0) FMA_STEP(pA1, pB1, (kb) + 1) \
                        FMA_STEP(pA2, pB2, (kb) + 2) FMA_STEP(pA3, pB3, (kb) + 3) }
#define FMA_GRP_Q(kb) { FMA_STEP(qA0, qB0, (kb) + 0) FMA_STEP(qA1, qB1, (kb) + 1) \
                        FMA_STEP(qA2, qB2, (kb) + 2) FMA_STEP(qA3, qB3, (kb) + 3) }

  LOADW_P(0)
  for (int c = 0; c < HH; c += 8) {     // 64 iterations, 8 k per iteration
    LOADW_Q(c + 4)                       // prefetch pong group
    FMA_GRP_P(c)                         // consume ping group
    if (c + 8 < HH) LOADW_P(c + 8)       // prefetch next ping group
    FMA_GRP_Q(c + 4)                     // consume pong group
  }

#undef LOADW_P
#undef LOADW_Q
#undef FMA_QUAD
#undef FMA_STEP
#undef FMA_GRP_P
#undef FMA_GRP_Q

  const float boA = bout[cA];
  const float boB = bout[cB];
#pragma unroll
  for (int ri = 0; ri < 32; ++ri) {     // FULL unroll: static acc indices
    float vA = okA ? (acc[ri][0] + boA) : -INFINITY;
    float vB = okB ? (acc[ri][1] + boB) : -INFINITY;
    // per-lane sorted-2 (pad to 4); cA < cB so tie keeps cA first
    float v[4]; int ix[4];
    if (vB > vA) { v[0] = vB; ix[0] = c0 + 64; v[1] = vA; ix[1] = okA ? c0 : 0x7fffffff; }
    else         { v[0] = vA; ix[0] = okA ? c0 : 0x7fffffff; v[1] = vB; ix[1] = okB ? (c0 + 64) : 0x7fffffff; }
    v[2] = -INFINITY; ix[2] = 0x7fffffff;
    v[3] = -INFINITY; ix[3] = 0x7fffffff;
    // butterfly merge across 64 lanes -> wave-wide top-4 (all lanes agree)
#pragma unroll
    for (int m = 1; m < 64; m <<= 1) {
      float ov[4]; int oix[4];
#pragma unroll
      for (int jj = 0; jj < 4; ++jj) {
        ov[jj] = __shfl_xor(v[jj], m, 64);
        oix[jj] = __shfl_xor(ix[jj], m, 64);
      }
      merge44(v, ix, ov, oix);
    }
    const float ms = v[0];
    double sl = 0.0;
    if (okA) sl += (double)expf(vA - ms);
    if (okB) sl += (double)expf(vB - ms);
#pragma unroll
    for (int m = 1; m < 64; m <<= 1) sl += __shfl_xor(sl, m, 64);
    if (ct == 0) {
      const int row = rowU + ri;
      SRec* rec = &sbuf[(size_t)row * NSTR + s];
#pragma unroll
      for (int jj = 0; jj < 4; ++jj) { rec->v[jj] = v[jj]; rec->ix[jj] = ix[jj]; }
      rec->ms = ms;
      rec->S = sl;
    }
  }
}

// Merge a sorted-4 list into a sorted-8 list (keep top-8).
__device__ inline void merge84(float* v, int* ix, const float* ov, const int* oix) {
  float rv[8]; int rix[8];
  int a = 0, b = 0;
#pragma unroll
  for (int t = 0; t < 8; ++t) {
    bool ta;
    if (a >= 8) ta = false;
    else if (b >= 4) ta = true;
    else ta = (v[a] > ov[b]) || (v[a] == ov[b] && ix[a] < oix[b]);
    if (ta) { rv[t] = v[a]; rix[t] = ix[a]; ++a; }
    else    { rv[t] = ov[b]; rix[t] = oix[b]; ++b; }
  }
#pragma unroll
  for (int t = 0; t < 8; ++t) { v[t] = rv[t]; ix[t] = rix[t]; }
}

__device__ inline void merge88(float* v, int* ix, const float* ov, const int* oix) {
  float rv[8]; int rix[8];
  int a = 0, b = 0;
#pragma unroll
  for (int t = 0; t < 8; ++t) {
    bool ta;
    if (a >= 8) ta = false;
    else if (b >= 8) ta = true;
    else ta = (v[a] > ov[b]) || (v[a] == ov[b] && ix[a] < oix[b]);
    if (ta) { rv[t] = v[a]; rix[t] = ix[a]; ++a; }
    else    { rv[t] = ov[b]; rix[t] = oix[b]; ++b; }
  }
#pragma unroll
  for (int t = 0; t < 8; ++t) { v[t] = rv[t]; ix[t] = rix[t]; }
}

// Per row: global top-8 by raw value, fp64 Z, then emulate fp32 log_softmax
// q = fl32(fl32(v-m) - L32) and output top-4 by (q desc, idx asc).
__global__ __launch_bounds__(64) void k_merge(const SRec* __restrict__ sbuf,
                                              float* __restrict__ topq,
                                              int* __restrict__ topi) {
  const int row = blockIdx.x;
  const int l = threadIdx.x;
  float lv[8]; int li[8];
#pragma unroll
  for (int jj = 0; jj < 8; ++jj) { lv[jj] = -INFINITY; li[jj] = 0x7fffffff; }
  float lms[7]; double lS[7];
  int ns = 0;
  for (int s = l; s < NSTR; s += 64) {
    const SRec* rec = &sbuf[(size_t)row * NSTR + s];
    float mv[4]; int mi[4];
#pragma unroll
    for (int jj = 0; jj < 4; ++jj) { mv[jj] = rec->v[jj]; mi[jj] = rec->ix[jj]; }
    lms[ns] = rec->ms;
    lS[ns] = rec->S;
    ++ns;
    merge84(lv, li, mv, mi);
  }
#pragma unroll
  for (int m = 1; m < 64; m <<= 1) {
    float ov[8]; int oi[8];
#pragma unroll
    for (int jj = 0; jj < 8; ++jj) {
      ov[jj] = __shfl_xor(lv[jj], m, 64);
      oi[jj] = __shfl_xor(li[jj], m, 64);
    }
    merge88(lv, li, ov, oi);
  }
  const float mg = lv[0];  // global max logit
  double Z = 0.0;
  for (int i = 0; i < ns; ++i) Z += lS[i] * (double)expf(lms[i] - mg);
#pragma unroll
  for (int m = 1; m < 64; m <<= 1) Z += __shfl_xor(Z, m, 64);
  const float Zf = (float)Z;
  const float L32 = (float)log((double)Zf);
  // fp32-quantized logp for top-8, re-sort by (q desc, idx asc)
  float q[8];
#pragma unroll
  for (int jj = 0; jj < 8; ++jj) {
    float g = lv[jj] - mg;   // fp32 sub
    q[jj] = g - L32;         // fp32 sub -> the ref's logp quantization
  }
  // insertion sort of 8 (full order comparator: q desc, idx asc)
  float sq[8]; int si[8];
#pragma unroll
  for (int jj = 0; jj < 8; ++jj) {
    float cv = q[jj]; int ci = li[jj];
    int pos = jj;
    for (int kk2 = 0; kk2 < jj; ++kk2) {
      if (cv > sq[kk2] || (cv == sq[kk2] && ci < si[kk2])) { pos = kk2; break; }
    }
    for (int kk2 = jj; kk2 > pos; --kk2) { sq[kk2] = sq[kk2 - 1]; si[kk2] = si[kk2 - 1]; }
    sq[pos] = cv; si[pos] = ci;
  }
  if (l == 0) {
#pragma unroll
    for (int jj = 0; jj < 4; ++jj) {
      topq[row * 4 + jj] = sq[jj];
      topi[row * 4 + jj] = si[jj];
    }
  }
}

// Beam transition per batch row: trans[f*4+to] = fl32(score_f + q), stable
// top-4 of 16 (flat-index ascending on ties == jnp stable argsort).
__global__ __launch_bounds__(64) void k_beam(const float* __restrict__ topq,
                                             const int* __restrict__ topi,
                                             float* __restrict__ scores,
                                             int* __restrict__ curx,
                                             int* __restrict__ bfrom) {
  const int b = threadIdx.x;  // 0..63
  float sc[4];
#pragma unroll
  for (int f = 0; f < 4; ++f) sc[f] = scores[f * 64 + b];
  float tv[16];
#pragma unroll
  for (int f = 0; f < 4; ++f)
#pragma unroll
    for (int to = 0; to < 4; ++to)
      tv[f * 4 + to] = sc[f] + topq[(f * 64 + b) * 4 + to];  // fp32 add

  float ov[4]; int ord[4]; int cnt = 0;
#pragma unroll
  for (int flat = 0; flat < 16; ++flat) {
    float v = tv[flat];
    int pos = -1;
    for (int j = 0; j < cnt; ++j)
      if (v > ov[j]) { pos = j; break; }   // strict: stable on equals
    if (pos < 0) {
      if (cnt < 4) { ov[cnt] = v; ord[cnt] = flat; ++cnt; }
    } else {
      int last = (cnt < 4) ? cnt : 3;
      for (int j = last; j > pos; --j) { ov[j] = ov[j - 1]; ord[j] = ord[j - 1]; }
      ov[pos] = v; ord[pos] = flat;
      if (cnt < 4) ++cnt;
    }
  }
#pragma unroll
  for (int s = 0; s < 4; ++s) {
    int flat = ord[s];
    int f = flat >> 2, to = flat & 3;
    int tok = topi[(f * 64 + b) * 4 + to];
    scores[s * 64 + b] = ov[s];
    curx[s * 64 + b] = tok;
    bfrom[s * 64 + b] = f;
  }
}

// Gather hidden states by source beam: hCur[j, s*64+b] = hStage[j, bfrom*64+b].
__global__ __launch_bounds__(256) void k_hgather(const float* __restrict__ hStage,
                                                 float* __restrict__ hCur,
                                                 const int* __restrict__ bfrom) {
  int idx = blockIdx.x * 256 + threadIdx.x;  // HH*RR = 131072
  int j = idx >> 8, r = idx & 255;
  int s = r >> 6, b = r & 63;
  hCur[(size_t)j * RR + r] = hStage[(size_t)j * RR + bfrom[s * 64 + b] * 64 + b];
}

// Gather sequences + append new token at position t. seqs layout [b][k][T].
__global__ __launch_bounds__(256) void k_seq(const int* __restrict__ src,
                                             int* __restrict__ dst,
                                             const int* __restrict__ bfrom,
                                             const int* __restrict__ curx,
                                             int t, int T) {
  int tid = threadIdx.x;  // 256 = 4 slots x 64 rows
  int s = tid >> 6, b = tid & 63;
  int bf = bfrom[s * 64 + b];
  for (int u = 0; u < t; ++u)
    dst[(b * KK + s) * T + u] = src[(b * KK + bf) * T + u];
  dst[(b * KK + s) * T + t] = curx[s * 64 + b];
}

__global__ __launch_bounds__(256) void k_out(const int* __restrict__ seqs,
                                             int* __restrict__ outp, int T) {
  int idx = blockIdx.x * 256 + threadIdx.x;
  if (idx < BB * T) {
    int b = idx / T, u = idx % T;
    outp[b * T + u] = seqs[(b * KK + 0) * T + u];
  }
}

extern "C" void kernel_launch(void* const* d_in, const int* in_sizes, int n_in,
                              void* d_out, int out_size, void* d_ws, size_t ws_size,
                              hipStream_t stream) {
  (void)in_sizes; (void)n_in; (void)ws_size;
  const int* xs = (const int*)d_in[0];
  const float* Etab = (const float*)d_in[1];
  const float* Wih = (const float*)d_in[2];
  const float* Whh = (const float*)d_in[3];
  const float* bih = (const float*)d_in[4];
  const float* bhh = (const float*)d_in[5];
  const float* Wout = (const float*)d_in[6];
  const float* bout = (const float*)d_in[7];
  int* outp = (int*)d_out;
  const int T = out_size / BB;  // 16

  // workspace carve (~6 MB)
  SRec* sbuf = (SRec*)d_ws;                       // 256*393*48 B
  float* hCur = (float*)(sbuf + (size_t)RR * NSTR);
  float* hStage = hCur + (size_t)HH * RR;
  float* topq = hStage + (size_t)HH * RR;         // RR*4 f
  int* topi = (int*)(topq + RR * 4);              // RR*4 i
  float* scores = (float*)(topi + RR * 4);        // RR f
  int* curx = (int*)(scores + RR);                // RR i
  int* bfrom = curx + RR;                         // RR i
  int* seqA = bfrom + RR;                         // BB*KK*T i
  int* seqB = seqA + BB * KK * T;                 // BB*KK*T i

  k_init<<<dim3(512), dim3(256), 0, stream>>>(xs, hCur, scores, curx);
  for (int t = 0; t < T; ++t) {
    int* ssrc = (t % 2 == 0) ? seqA : seqB;
    int* sdst = (t % 2 == 0) ? seqB : seqA;
    k_gru<<<dim3(64, 4), dim3(256), 0, stream>>>(Etab, Wih, Whh, bih, bhh,
                                                 hCur, hStage, curx);
    k_logits<<<dim3(NSTR, 2), dim3(256), 0, stream>>>(Wout, bout, hStage, sbuf);
    k_merge<<<dim3(RR), dim3(64), 0, stream>>>(sbuf, topq, topi);
    k_beam<<<dim3(1), dim3(64), 0, stream>>>(topq, topi, scores, curx, bfrom);
    k_hgather<<<dim3(512), dim3(256), 0, stream>>>(hStage, hCur, bfrom);
    k_seq<<<dim3(1), dim3(256), 0, stream>>>(ssrc, sdst, bfrom, curx, t, T);
  }
  int* sfin = (T % 2 == 0) ? seqA : seqB;
  k_out<<<dim3((BB * T + 255) / 256), dim3(256), 0, stream>>>(sfin, outp, T);
}

// Round 6
// 10146.626 us; speedup vs baseline: 5.3745x; 2.4445x over previous
//
#include <hip/hip_runtime.h>
#include <math.h>

#define BB 64      // batch
#define KK 4       // beam width
#define RR 256     // KK*BB rows
#define DD 512
#define HH 512
#define T3 1536
#define VV 50257
#define NSTR 393   // ceil(VV/128)

struct SRec {       // per (row, stripe) record, 48 B
  float v[4];       // stripe top-4 logits (desc, idx-asc on ties)
  int   ix[4];
  float ms;         // stripe max (== v[0])
  float pad;
  double S;         // sum expf(v - ms) over stripe, fp64 accumulated
};

__global__ __launch_bounds__(256) void k_init(const int* __restrict__ xs,
                                              float* __restrict__ hCur,
                                              float* __restrict__ scores,
                                              int* __restrict__ curx) {
  int i = blockIdx.x * 256 + threadIdx.x;
  if (i < HH * RR) hCur[i] = 0.0f;
  if (i < RR) {
    scores[i] = 0.0f;
    curx[i] = xs[i & 63];
  }
}

// GRU for 256 beam-rows, fp32, fixed sequential k-order (deterministic, so
// bit-identical beam rows stay bit-identical). grid (64 jg, 4 rowgroup).
__global__ __launch_bounds__(256) void k_gru(const float* __restrict__ Etab,
                                             const float* __restrict__ Wih,
                                             const float* __restrict__ Whh,
                                             const float* __restrict__ bih,
                                             const float* __restrict__ bhh,
                                             const float* __restrict__ hCur,
                                             float* __restrict__ hStage,
                                             const int* __restrict__ curx) {
  const int tid = threadIdx.x;
  const int jloc = tid & 7;
  const int bg = tid >> 3;
  const int j = blockIdx.x * 8 + jloc;
  const int rowbase = blockIdx.y * 64;
  const int b0 = bg * 2;  // local row pair within group

  __shared__ float xe[64 * 33];
  __shared__ float hp[64 * 33];
  __shared__ int xl[64];
  if (tid < 64) xl[tid] = curx[rowbase + tid];

  float a[12];
#pragma unroll
  for (int i = 0; i < 12; ++i) a[i] = 0.0f;

  for (int kt = 0; kt < 16; ++kt) {
    __syncthreads();
    const int kb = kt * 32;
#pragma unroll
    for (int i = 0; i < 8; ++i) {
      int idx = i * 256 + tid;
      int b = idx >> 5, kk = idx & 31;
      xe[b * 33 + kk] = Etab[(size_t)xl[b] * DD + kb + kk];
    }
#pragma unroll
    for (int i = 0; i < 8; ++i) {
      int idx = i * 256 + tid;
      int kk = idx >> 6, bl = idx & 63;
      hp[bl * 33 + kk] = hCur[(size_t)(kb + kk) * RR + rowbase + bl];
    }
    __syncthreads();
#pragma unroll 4
    for (int kk = 0; kk < 32; ++kk) {
      const size_t krow = (size_t)(kb + kk) * T3;
      float wir = Wih[krow + j];
      float wiz = Wih[krow + j + HH];
      float wig = Wih[krow + j + 2 * HH];
      float whr = Whh[krow + j];
      float whz = Whh[krow + j + HH];
      float whg = Whh[krow + j + 2 * HH];
      float x0v = xe[b0 * 33 + kk];
      float x1v = xe[(b0 + 1) * 33 + kk];
      float h0v = hp[b0 * 33 + kk];
      float h1v = hp[(b0 + 1) * 33 + kk];
      a[0] += x0v * wir; a[1]  += x0v * wiz; a[2]  += x0v * wig;
      a[3] += h0v * whr; a[4]  += h0v * whz; a[5]  += h0v * whg;
      a[6] += x1v * wir; a[7]  += x1v * wiz; a[8]  += x1v * wig;
      a[9] += h1v * whr; a[10] += h1v * whz; a[11] += h1v * whg;
    }
  }

  const float bir = bih[j], biz = bih[HH + j], big = bih[2 * HH + j];
  const float bhr = bhh[j], bhz = bhh[HH + j], bhg = bhh[2 * HH + j];
#pragma unroll
  for (int p = 0; p < 2; ++p) {
    const int row = rowbase + b0 + p;
    float ir = a[6 * p + 0] + bir;
    float iz = a[6 * p + 1] + biz;
    float ig = a[6 * p + 2] + big;
    float hr = a[6 * p + 3] + bhr;
    float hz = a[6 * p + 4] + bhz;
    float hg = a[6 * p + 5] + bhg;
    float r = 1.0f / (1.0f + expf(-(ir + hr)));
    float z = 1.0f / (1.0f + expf(-(iz + hz)));
    float n = tanhf(ig + r * hg);
    float hprev = hCur[(size_t)j * RR + row];
    hStage[(size_t)j * RR + row] = (1.0f - z) * n + z * hprev;
  }
}

// Merge two sorted-4 lists (desc value, asc index on ties), keep top-4.
__device__ __forceinline__ void merge44(float* v, int* ix, const float* ov, const int* oix) {
  float rv[4]; int rix[4];
  int a = 0, b = 0;
#pragma unroll
  for (int t = 0; t < 4; ++t) {
    bool ta;
    if (a >= 4) ta = false;
    else if (b >= 4) ta = true;
    else ta = (v[a] > ov[b]) || (v[a] == ov[b] && ix[a] < oix[b]);
    if (ta) { rv[t] = v[a]; rix[t] = ix[a]; ++a; }
    else    { rv[t] = ov[b]; rix[t] = oix[b]; ++b; }
  }
#pragma unroll
  for (int t = 0; t < 4; ++t) { v[t] = rv[t]; ix[t] = rix[t]; }
}

// Per-row epilogue for k_logits: wave-wide top-4 butterfly + stripe exp-sum.
// Takes the two accumulators BY VALUE so the acc array is never
// runtime-indexed (round-5 lesson: the unroller bails on 32 big-body
// iterations, leaving acc[ri] dynamic -> whole acc demoted to scratch ->
// 6 GB/dispatch of spill traffic).
__device__ __forceinline__ void epi_one(float accA, float accB, int c0,
                                        bool okA, bool okB, float boA, float boB,
                                        int row, int s, int ct,
                                        SRec* __restrict__ sbuf) {
  float vA = okA ? (accA + boA) : -INFINITY;
  float vB = okB ? (accB + boB) : -INFINITY;
  // per-lane sorted-2 (pad to 4); cA < cB so tie keeps cA first
  float v[4]; int ix[4];
  if (vB > vA) { v[0] = vB; ix[0] = c0 + 64; v[1] = vA; ix[1] = okA ? c0 : 0x7fffffff; }
  else         { v[0] = vA; ix[0] = okA ? c0 : 0x7fffffff; v[1] = vB; ix[1] = okB ? (c0 + 64) : 0x7fffffff; }
  v[2] = -INFINITY; ix[2] = 0x7fffffff;
  v[3] = -INFINITY; ix[3] = 0x7fffffff;
  // butterfly merge across 64 lanes -> wave-wide top-4 (all lanes agree)
#pragma unroll
  for (int m = 1; m < 64; m <<= 1) {
    float ov[4]; int oix[4];
#pragma unroll
    for (int jj = 0; jj < 4; ++jj) {
      ov[jj] = __shfl_xor(v[jj], m, 64);
      oix[jj] = __shfl_xor(ix[jj], m, 64);
    }
    merge44(v, ix, ov, oix);
  }
  const float ms = v[0];
  double sl = 0.0;
  if (okA) sl += (double)expf(vA - ms);
  if (okB) sl += (double)expf(vB - ms);
#pragma unroll
  for (int m = 1; m < 64; m <<= 1) sl += __shfl_xor(sl, m, 64);
  if (ct == 0) {
    SRec* rec = &sbuf[(size_t)row * NSTR + s];
#pragma unroll
    for (int jj = 0; jj < 4; ++jj) { rec->v[jj] = v[jj]; rec->ix[jj] = ix[jj]; }
    rec->ms = ms;
    rec->S = sl;
  }
}

// logits (fp32) for 256 rows; per (row, 128-col stripe): top-4 by value
// (idx-asc ties) + stripe max + stripe exp-sum. grid (393, 2 rowgroups of
// 128 rows), block 256 = 4 waves x 32 rows.
// v7: v6 main loop (32 rows/wave, no LDS/barriers, ping-pong W in named
// scalars, wave-uniform scalar h, all acc indices literal) + spill-proof
// epilogue: 32 explicit macro-expanded calls passing acc BY VALUE (no
// loop, so no unroller bail, no runtime indexing of acc anywhere).
// __launch_bounds__(256,2): VGPR budget 256 (need ~140), 3 waves/SIMD
// matches the 3144-wave grid. FMA accumulation order (k ascending, single
// fmac chain per row/col) is bit-identical to all previous versions.
__global__ __launch_bounds__(256, 2) void k_logits(const float* __restrict__ Wout,
                                                   const float* __restrict__ bout,
                                                   const float* __restrict__ hStage,
                                                   SRec* __restrict__ sbuf) {
  const int s = blockIdx.x;
  const int tid = threadIdx.x;
  const int wid = tid >> 6;     // wave -> local rows wid*32 .. +31
  const int ct = tid & 63;
  const int scol = s * 128;
  const int c0 = scol + ct;
  const bool okA = (c0 < VV);
  const bool okB = (c0 + 64 < VV);
  const int cA = okA ? c0 : (VV - 1);
  const int cB = okB ? (c0 + 64) : (VV - 1);
  // wave-uniform row base (forced uniform -> scalar loads for h)
  const int rowU = __builtin_amdgcn_readfirstlane(blockIdx.y * 128 + wid * 32);

  const float* __restrict__ WA = Wout + cA;   // per-lane column base, stride VV
  const float* __restrict__ WB = Wout + cB;

  float acc[32][2];
#pragma unroll
  for (int ri = 0; ri < 32; ++ri) { acc[ri][0] = 0.0f; acc[ri][1] = 0.0f; }

  // W ping (p*) / pong (q*) buffers: named scalars, never address-taken.
  float pA0, pA1, pA2, pA3, pB0, pB1, pB2, pB3;
  float qA0, qA1, qA2, qA3, qB0, qB1, qB2, qB3;

#define LOADW_P(kb) {                                              \
    pA0 = WA[(size_t)((kb) + 0) * VV]; pB0 = WB[(size_t)((kb) + 0) * VV]; \
    pA1 = WA[(size_t)((kb) + 1) * VV]; pB1 = WB[(size_t)((kb) + 1) * VV]; \
    pA2 = WA[(size_t)((kb) + 2) * VV]; pB2 = WB[(size_t)((kb) + 2) * VV]; \
    pA3 = WA[(size_t)((kb) + 3) * VV]; pB3 = WB[(size_t)((kb) + 3) * VV]; }
#define LOADW_Q(kb) {                                              \
    qA0 = WA[(size_t)((kb) + 0) * VV]; qB0 = WB[(size_t)((kb) + 0) * VV]; \
    qA1 = WA[(size_t)((kb) + 1) * VV]; qB1 = WB[(size_t)((kb) + 1) * VV]; \
    qA2 = WA[(size_t)((kb) + 2) * VV]; qB2 = WB[(size_t)((kb) + 2) * VV]; \
    qA3 = WA[(size_t)((kb) + 3) * VV]; qB3 = WB[(size_t)((kb) + 3) * VV]; }

  // 4 rows of FMA from one float4 of h; all acc indices literal constants.
#define FMA_QUAD(g, base, wa, wb) {                       \
    acc[(base) + 0][0] += (g).x * (wa); acc[(base) + 0][1] += (g).x * (wb); \
    acc[(base) + 1][0] += (g).y * (wa); acc[(base) + 1][1] += (g).y * (wb); \
    acc[(base) + 2][0] += (g).z * (wa); acc[(base) + 2][1] += (g).z * (wb); \
    acc[(base) + 3][0] += (g).w * (wa); acc[(base) + 3][1] += (g).w * (wb); }

  // One k-step: 128 B wave-uniform h fetch + 64 FMAs.
#define FMA_STEP(wa, wb, kabs) {                                          \
    const float4* hg = reinterpret_cast<const float4*>(                   \
        hStage + (size_t)(kabs) * RR + rowU);                             \
    const float4 g0 = hg[0], g1 = hg[1], g2 = hg[2], g3 = hg[3];          \
    const float4 g4 = hg[4], g5 = hg[5], g6 = hg[6], g7 = hg[7];          \
    FMA_QUAD(g0,  0, wa, wb) FMA_QUAD(g1,  4, wa, wb)                     \
    FMA_QUAD(g2,  8, wa, wb) FMA_QUAD(g3, 12, wa, wb)                     \
    FMA_QUAD(g4, 16, wa, wb) FMA_QUAD(g5, 20, wa, wb)                     \
    FMA_QUAD(g6, 24, wa, wb) FMA_QUAD(g7, 28, wa, wb) }

#define FMA_GRP_P(kb) { FMA_STEP(pA0, pB0, (kb) + 0) FMA_STEP(pA1, pB1, (kb) + 1) \
                        FMA_STEP(pA2, pB2, (kb) + 2) FMA_STEP(pA3, pB3, (kb) + 3) }
#define FMA_GRP_Q(kb) { FMA_STEP(qA0, qB0, (kb) + 0) FMA_STEP(qA1, qB1, (kb) + 1) \
                        FMA_STEP(qA2, qB2, (kb) + 2) FMA_STEP(qA3, qB3, (kb) + 3) }

  LOADW_P(0)
  for (int c = 0; c < HH; c += 8) {     // 64 iterations, 8 k per iteration
    LOADW_Q(c + 4)                       // prefetch pong group
    FMA_GRP_P(c)                         // consume ping group
    if (c + 8 < HH) LOADW_P(c + 8)       // prefetch next ping group
    FMA_GRP_Q(c + 4)                     // consume pong group
  }

#undef LOADW_P
#undef LOADW_Q
#undef FMA_QUAD
#undef FMA_STEP
#undef FMA_GRP_P
#undef FMA_GRP_Q

  const float boA = bout[cA];
  const float boB = bout[cB];

  // 32 explicit epilogue expansions: acc passed by value, i literal.
#define EPI(i) epi_one(acc[i][0], acc[i][1], c0, okA, okB, boA, boB, \
                       rowU + (i), s, ct, sbuf);
  EPI(0)  EPI(1)  EPI(2)  EPI(3)  EPI(4)  EPI(5)  EPI(6)  EPI(7)
  EPI(8)  EPI(9)  EPI(10) EPI(11) EPI(12) EPI(13) EPI(14) EPI(15)
  EPI(16) EPI(17) EPI(18) EPI(19) EPI(20) EPI(21) EPI(22) EPI(23)
  EPI(24) EPI(25) EPI(26) EPI(27) EPI(28) EPI(29) EPI(30) EPI(31)
#undef EPI
}

// Merge a sorted-4 list into a sorted-8 list (keep top-8).
__device__ inline void merge84(float* v, int* ix, const float* ov, const int* oix) {
  float rv[8]; int rix[8];
  int a = 0, b = 0;
#pragma unroll
  for (int t = 0; t < 8; ++t) {
    bool ta;
    if (a >= 8) ta = false;
    else if (b >= 4) ta = true;
    else ta = (v[a] > ov[b]) || (v[a] == ov[b] && ix[a] < oix[b]);
    if (ta) { rv[t] = v[a]; rix[t] = ix[a]; ++a; }
    else    { rv[t] = ov[b]; rix[t] = oix[b]; ++b; }
  }
#pragma unroll
  for (int t = 0; t < 8; ++t) { v[t] = rv[t]; ix[t] = rix[t]; }
}

__device__ inline void merge88(float* v, int* ix, const float* ov, const int* oix) {
  float rv[8]; int rix[8];
  int a = 0, b = 0;
#pragma unroll
  for (int t = 0; t < 8; ++t) {
    bool ta;
    if (a >= 8) ta = false;
    else if (b >= 8) ta = true;
    else ta = (v[a] > ov[b]) || (v[a] == ov[b] && ix[a] < oix[b]);
    if (ta) { rv[t] = v[a]; rix[t] = ix[a]; ++a; }
    else    { rv[t] = ov[b]; rix[t] = oix[b]; ++b; }
  }
#pragma unroll
  for (int t = 0; t < 8; ++t) { v[t] = rv[t]; ix[t] = rix[t]; }
}

// Per row: global top-8 by raw value, fp64 Z, then emulate fp32 log_softmax
// q = fl32(fl32(v-m) - L32) and output top-4 by (q desc, idx asc).
__global__ __launch_bounds__(64) void k_merge(const SRec* __restrict__ sbuf,
                                              float* __restrict__ topq,
                                              int* __restrict__ topi) {
  const int row = blockIdx.x;
  const int l = threadIdx.x;
  float lv[8]; int li[8];
#pragma unroll
  for (int jj = 0; jj < 8; ++jj) { lv[jj] = -INFINITY; li[jj] = 0x7fffffff; }
  float lms[7]; double lS[7];
  int ns = 0;
  for (int s = l; s < NSTR; s += 64) {
    const SRec* rec = &sbuf[(size_t)row * NSTR + s];
    float mv[4]; int mi[4];
#pragma unroll
    for (int jj = 0; jj < 4; ++jj) { mv[jj] = rec->v[jj]; mi[jj] = rec->ix[jj]; }
    lms[ns] = rec->ms;
    lS[ns] = rec->S;
    ++ns;
    merge84(lv, li, mv, mi);
  }
#pragma unroll
  for (int m = 1; m < 64; m <<= 1) {
    float ov[8]; int oi[8];
#pragma unroll
    for (int jj = 0; jj < 8; ++jj) {
      ov[jj] = __shfl_xor(lv[jj], m, 64);
      oi[jj] = __shfl_xor(li[jj], m, 64);
    }
    merge88(lv, li, ov, oi);
  }
  const float mg = lv[0];  // global max logit
  double Z = 0.0;
  for (int i = 0; i < ns; ++i) Z += lS[i] * (double)expf(lms[i] - mg);
#pragma unroll
  for (int m = 1; m < 64; m <<= 1) Z += __shfl_xor(Z, m, 64);
  const float Zf = (float)Z;
  const float L32 = (float)log((double)Zf);
  // fp32-quantized logp for top-8, re-sort by (q desc, idx asc)
  float q[8];
#pragma unroll
  for (int jj = 0; jj < 8; ++jj) {
    float g = lv[jj] - mg;   // fp32 sub
    q[jj] = g - L32;         // fp32 sub -> the ref's logp quantization
  }
  // insertion sort of 8 (full order comparator: q desc, idx asc)
  float sq[8]; int si[8];
#pragma unroll
  for (int jj = 0; jj < 8; ++jj) {
    float cv = q[jj]; int ci = li[jj];
    int pos = jj;
    for (int kk2 = 0; kk2 < jj; ++kk2) {
      if (cv > sq[kk2] || (cv == sq[kk2] && ci < si[kk2])) { pos = kk2; break; }
    }
    for (int kk2 = jj; kk2 > pos; --kk2) { sq[kk2] = sq[kk2 - 1]; si[kk2] = si[kk2 - 1]; }
    sq[pos] = cv; si[pos] = ci;
  }
  if (l == 0) {
#pragma unroll
    for (int jj = 0; jj < 4; ++jj) {
      topq[row * 4 + jj] = sq[jj];
      topi[row * 4 + jj] = si[jj];
    }
  }
}

// Beam transition per batch row: trans[f*4+to] = fl32(score_f + q), stable
// top-4 of 16 (flat-index ascending on ties == jnp stable argsort).
__global__ __launch_bounds__(64) void k_beam(const float* __restrict__ topq,
                                             const int* __restrict__ topi,
                                             float* __restrict__ scores,
                                             int* __restrict__ curx,
                                             int* __restrict__ bfrom) {
  const int b = threadIdx.x;  // 0..63
  float sc[4];
#pragma unroll
  for (int f = 0; f < 4; ++f) sc[f] = scores[f * 64 + b];
  float tv[16];
#pragma unroll
  for (int f = 0; f < 4; ++f)
#pragma unroll
    for (int to = 0; to < 4; ++to)
      tv[f * 4 + to] = sc[f] + topq[(f * 64 + b) * 4 + to];  // fp32 add

  float ov[4]; int ord[4]; int cnt = 0;
#pragma unroll
  for (int flat = 0; flat < 16; ++flat) {
    float v = tv[flat];
    int pos = -1;
    for (int j = 0; j < cnt; ++j)
      if (v > ov[j]) { pos = j; break; }   // strict: stable on equals
    if (pos < 0) {
      if (cnt < 4) { ov[cnt] = v; ord[cnt] = flat; ++cnt; }
    } else {
      int last = (cnt < 4) ? cnt : 3;
      for (int j = last; j > pos; --j) { ov[j] = ov[j - 1]; ord[j] = ord[j - 1]; }
      ov[pos] = v; ord[pos] = flat;
      if (cnt < 4) ++cnt;
    }
  }
#pragma unroll
  for (int s = 0; s < 4; ++s) {
    int flat = ord[s];
    int f = flat >> 2, to = flat & 3;
    int tok = topi[(f * 64 + b) * 4 + to];
    scores[s * 64 + b] = ov[s];
    curx[s * 64 + b] = tok;
    bfrom[s * 64 + b] = f;
  }
}

// Gather hidden states by source beam: hCur[j, s*64+b] = hStage[j, bfrom*64+b].
__global__ __launch_bounds__(256) void k_hgather(const float* __restrict__ hStage,
                                                 float* __restrict__ hCur,
                                                 const int* __restrict__ bfrom) {
  int idx = blockIdx.x * 256 + threadIdx.x;  // HH*RR = 131072
  int j = idx >> 8, r = idx & 255;
  int s = r >> 6, b = r & 63;
  hCur[(size_t)j * RR + r] = hStage[(size_t)j * RR + bfrom[s * 64 + b] * 64 + b];
}

// Gather sequences + append new token at position t. seqs layout [b][k][T].
__global__ __launch_bounds__(256) void k_seq(const int* __restrict__ src,
                                             int* __restrict__ dst,
                                             const int* __restrict__ bfrom,
                                             const int* __restrict__ curx,
                                             int t, int T) {
  int tid = threadIdx.x;  // 256 = 4 slots x 64 rows
  int s = tid >> 6, b = tid & 63;
  int bf = bfrom[s * 64 + b];
  for (int u = 0; u < t; ++u)
    dst[(b * KK + s) * T + u] = src[(b * KK + bf) * T + u];
  dst[(b * KK + s) * T + t] = curx[s * 64 + b];
}

__global__ __launch_bounds__(256) void k_out(const int* __restrict__ seqs,
                                             int* __restrict__ outp, int T) {
  int idx = blockIdx.x * 256 + threadIdx.x;
  if (idx < BB * T) {
    int b = idx / T, u = idx % T;
    outp[b * T + u] = seqs[(b * KK + 0) * T + u];
  }
}

extern "C" void kernel_launch(void* const* d_in, const int* in_sizes, int n_in,
                              void* d_out, int out_size, void* d_ws, size_t ws_size,
                              hipStream_t stream) {
  (void)in_sizes; (void)n_in; (void)ws_size;
  const int* xs = (const int*)d_in[0];
  const float* Etab = (const float*)d_in[1];
  const float* Wih = (const float*)d_in[2];
  const float* Whh = (const float*)d_in[3];
  const float* bih = (const float*)d_in[4];
  const float* bhh = (const float*)d_in[5];
  const float* Wout = (const float*)d_in[6];
  const float* bout = (const float*)d_in[7];
  int* outp = (int*)d_out;
  const int T = out_size / BB;  // 16

  // workspace carve (~6 MB)
  SRec* sbuf = (SRec*)d_ws;                       // 256*393*48 B
  float* hCur = (float*)(sbuf + (size_t)RR * NSTR);
  float* hStage = hCur + (size_t)HH * RR;
  float* topq = hStage + (size_t)HH * RR;         // RR*4 f
  int* topi = (int*)(topq + RR * 4);              // RR*4 i
  float* scores = (float*)(topi + RR * 4);        // RR f
  int* curx = (int*)(scores + RR);                // RR i
  int* bfrom = curx + RR;                         // RR i
  int* seqA = bfrom + RR;                         // BB*KK*T i
  int* seqB = seqA + BB * KK * T;                 // BB*KK*T i

  k_init<<<dim3(512), dim3(256), 0, stream>>>(xs, hCur, scores, curx);
  for (int t = 0; t < T; ++t) {
    int* ssrc = (t % 2 == 0) ? seqA : seqB;
    int* sdst = (t % 2 == 0) ? seqB : seqA;
    k_gru<<<dim3(64, 4), dim3(256), 0, stream>>>(Etab, Wih, Whh, bih, bhh,
                                                 hCur, hStage, curx);
    k_logits<<<dim3(NSTR, 2), dim3(256), 0, stream>>>(Wout, bout, hStage, sbuf);
    k_merge<<<dim3(RR), dim3(64), 0, stream>>>(sbuf, topq, topi);
    k_beam<<<dim3(1), dim3(64), 0, stream>>>(topq, topi, scores, curx, bfrom);
    k_hgather<<<dim3(512), dim3(256), 0, stream>>>(hStage, hCur, bfrom);
    k_seq<<<dim3(1), dim3(256), 0, stream>>>(ssrc, sdst, bfrom, curx, t, T);
  }
  int* sfin = (T % 2 == 0) ? seqA : seqB;
  k_out<<<dim3((BB * T + 255) / 256), dim3(256), 0, stream>>>(sfin, outp, T);
}